// Round 11
// baseline (96.156 us; speedup 1.0000x reference)
//
#include <hip/hip_runtime.h>
#include <math.h>

#define B_ 32
#define T_ 512
#define D_ 256
#define KTOT 768             // 3 taps x 256 channels
#define NSTEP 24             // KTOT / 32
#define TILE_M 64
#define APITCH 264           // bf16 elems per A-LDS row (528B, breaks alignment)
#define BBUF 16384           // one B stage: 256 rows x 32 bf16

typedef __bf16 bf16x8 __attribute__((ext_vector_type(8)));
typedef __bf16 bf16x4 __attribute__((ext_vector_type(4)));
typedef float  f32x4  __attribute__((ext_vector_type(4)));

__device__ __forceinline__ void gload16(const void* g, void* l) {
    __builtin_amdgcn_global_load_lds(
        (const __attribute__((address_space(1))) unsigned int*)g,
        (__attribute__((address_space(3))) unsigned int*)l, 16, 0, 0);
}

// B ring-3 stage: 1024 chunks of 16B; 512 threads -> 2 loads/thread (uniform).
#define BSTAGE(kstep, buf)                                              \
    do {                                                                \
        _Pragma("unroll")                                               \
        for (int pp = 0; pp < 2; ++pp) {                                \
            int c = pp * 512 + tid;                                     \
            int n = c >> 2, scb = (c & 3) ^ (n & 3);                    \
            gload16(bmat + (size_t)n * KTOT + (kstep) * 32 + scb * 8,   \
                    Bring + (buf) * BBUF + c * 16);                     \
        }                                                               \
    } while (0)

// Main loop: depth-2 B prefetch, counted vmcnt(2), one barrier per step.
#define RUN_PIPE(COMPUTE)                                               \
    _Pragma("unroll")                                                   \
    for (int k = 0; k < NSTEP; ++k) {                                   \
        if (k < NSTEP - 1) asm volatile("s_waitcnt vmcnt(2)" ::: "memory"); \
        else               asm volatile("s_waitcnt vmcnt(0)" ::: "memory"); \
        __builtin_amdgcn_s_barrier();                                   \
        if (k + 2 < NSTEP) BSTAGE(k + 2, (k + 2) % 3);                  \
        COMPUTE(k);                                                     \
    }

// ---------------------------------------------------------------------------
// conv1: A = 66 fp32 x-rows preloaded once -> bf16 LDS tile [66][264];
// per step only B is staged.  512 thr / 8 waves; wave = 64 rows x 32 cols
// (acc[4][2]).  Epilogue: bias/ReLU/LayerNorm -> bf16 h1pad rows 1..512.
// ---------------------------------------------------------------------------
__global__ __launch_bounds__(512) void gemm1_ln_kernel(
    const float* __restrict__ x,       // (B,512,256) fp32
    const __bf16* __restrict__ bmat,   // (256,768)
    const float* __restrict__ bias,
    const float* __restrict__ gamma,
    const float* __restrict__ beta,
    __bf16* __restrict__ dst)          // h1pad (B,514,256)
{
    __shared__ __align__(16) __bf16 Axs[66 * APITCH];
    __shared__ __align__(16) unsigned char Bring[3 * BBUF];
    __shared__ float part[64 * 8 * 2];
    __shared__ float tot[64 * 2];
    const int tid = threadIdx.x, lane = tid & 63, wid = tid >> 6;
    const int p = lane & 15, q = lane >> 4;
    const int m0 = blockIdx.x * TILE_M;
    const int bb = m0 >> 9, t0 = m0 & 511;
    const float* xb = x + (size_t)bb * T_ * D_;

    // ---- A preload: 4224 chunks of 4 f32 -> cvt -> 8B LDS write ----
#pragma unroll
    for (int i = 0; i < 9; ++i) {
        int c = tid + 512 * i;
        if (c < 4224) {
            int u = c >> 6, cf = c & 63;
            int t = t0 - 1 + u;
            bool v = ((unsigned)t < (unsigned)T_);
            f32x4 xv = *(const f32x4*)(xb + (size_t)(v ? t : 0) * D_ + cf * 4);
            bf16x4 o;
#pragma unroll
            for (int e = 0; e < 4; ++e) o[e] = (__bf16)(v ? xv[e] : 0.f);
            *(bf16x4*)(&Axs[u * APITCH + cf * 4]) = o;
        }
    }
    BSTAGE(0, 0); BSTAGE(1, 1);
    __syncthreads();   // drains A-writes + B stages 0,1 (prologue only)

    f32x4 acc[4][2];
#pragma unroll
    for (int mf = 0; mf < 4; ++mf)
#pragma unroll
        for (int nf = 0; nf < 2; ++nf)
            acc[mf][nf] = (f32x4){0.f, 0.f, 0.f, 0.f};

    auto COMPUTE = [&](int kstep) {
        const int tap = kstep >> 3;
        const int co = (kstep & 7) * 64;   // byte col offset within A row
        const unsigned char* Ab = (const unsigned char*)Axs;
        unsigned char* Bb = Bring + (kstep % 3) * BBUF;
        const int swz = (q ^ (p & 3)) * 16;
        bf16x8 a[4], bv[2];
#pragma unroll
        for (int mf = 0; mf < 4; ++mf)
            a[mf] = *(const bf16x8*)(Ab + (mf * 16 + p + tap) * (APITCH * 2)
                                     + co + q * 16);
#pragma unroll
        for (int nf = 0; nf < 2; ++nf)
            bv[nf] = *(const bf16x8*)(Bb + (wid * 32 + nf * 16 + p) * 64 + swz);
#pragma unroll
        for (int mf = 0; mf < 4; ++mf)
#pragma unroll
            for (int nf = 0; nf < 2; ++nf)
                acc[mf][nf] = __builtin_amdgcn_mfma_f32_16x16x32_bf16(
                    a[mf], bv[nf], acc[mf][nf], 0, 0, 0);
    };

    RUN_PIPE(COMPUTE)

    // ---- epilogue: bias+ReLU -> cross-wave LN -> bf16 h1pad ----
    float bcol[2], gcol[2], becol[2];
#pragma unroll
    for (int nf = 0; nf < 2; ++nf) {
        int c = wid * 32 + nf * 16 + p;
        bcol[nf] = bias[c]; gcol[nf] = gamma[c]; becol[nf] = beta[c];
    }
#pragma unroll
    for (int mf = 0; mf < 4; ++mf)
#pragma unroll
        for (int r = 0; r < 4; ++r) {
            float s = 0.f, s2 = 0.f;
#pragma unroll
            for (int nf = 0; nf < 2; ++nf) {
                float y = fmaxf(acc[mf][nf][r] + bcol[nf], 0.f);
                s += y; s2 += y * y;
            }
#pragma unroll
            for (int off = 8; off >= 1; off >>= 1) {
                s += __shfl_xor(s, off); s2 += __shfl_xor(s2, off);
            }
            if (p == 0) {
                int row = mf * 16 + q * 4 + r;
                part[(row * 8 + wid) * 2]     = s;
                part[(row * 8 + wid) * 2 + 1] = s2;
            }
        }
    __syncthreads();
    if (tid < 64) {
        float s = 0.f, s2 = 0.f;
#pragma unroll
        for (int w = 0; w < 8; ++w) {
            s  += part[(tid * 8 + w) * 2];
            s2 += part[(tid * 8 + w) * 2 + 1];
        }
        float m = s * (1.f / 256.f);
        float v = s2 * (1.f / 256.f) - m * m;
        tot[tid * 2]     = m;
        tot[tid * 2 + 1] = rsqrtf(v + 1e-5f);
    }
    __syncthreads();
#pragma unroll
    for (int mf = 0; mf < 4; ++mf)
#pragma unroll
        for (int r = 0; r < 4; ++r) {
            int row = mf * 16 + q * 4 + r;
            float m  = tot[row * 2];
            float rs = tot[row * 2 + 1];
            size_t gb = ((size_t)bb * (T_ + 2) + 1 + t0 + row) * D_;
#pragma unroll
            for (int nf = 0; nf < 2; ++nf) {
                int c = wid * 32 + nf * 16 + p;
                float y = fmaxf(acc[mf][nf][r] + bcol[nf], 0.f);
                dst[gb + c] = (__bf16)((y - m) * rs * gcol[nf] + becol[nf]);
            }
        }
}

// ---------------------------------------------------------------------------
// conv2 + gather, phase-sequential per block: every block computes its 64-row
// conv2 tile (A preloaded once from h1pad, B ring-staged), writes pred via the
// folded LN+linear, then falls through to a grid-strided slice of the gather
// (no LDS needed) — early-finishing blocks stream HBM while others compute.
// ---------------------------------------------------------------------------
__global__ __launch_bounds__(512) void gemm2_pred_gather_kernel(
    const __bf16* __restrict__ h1pad,  // (B, 514, 256)
    const __bf16* __restrict__ bmat,
    const float* __restrict__ bias,
    const float* __restrict__ gamma,
    const float* __restrict__ beta,
    const float* __restrict__ wl,
    const float* __restrict__ bl,
    float* __restrict__ pred,          // (B, T)
    const float* __restrict__ x,       // (B,512,256) fp32
    const int* __restrict__ ends,
    float* __restrict__ out,           // (B,maxLen,256)
    int maxLen, int doGather)
{
    __shared__ __align__(16) __bf16 Axs[66 * APITCH];
    __shared__ __align__(16) unsigned char Bring[3 * BBUF];
    __shared__ float part[64 * 8 * 4];
    __shared__ float sg[2];
    const int tid = threadIdx.x, lane = tid & 63, wid = tid >> 6;
    const int p = lane & 15, q = lane >> 4;
    const int m0 = blockIdx.x * TILE_M;
    const int bb = m0 >> 9, t0 = m0 & 511;

    if (tid < 64) {   // Sgw = sum g*wl, Sbw = sum be*wl + bl
        f32x4 g  = *(const f32x4*)(gamma + 4 * tid);
        f32x4 be = *(const f32x4*)(beta  + 4 * tid);
        f32x4 w  = *(const f32x4*)(wl    + 4 * tid);
        float a = g[0]*w[0] + g[1]*w[1] + g[2]*w[2] + g[3]*w[3];
        float b = be[0]*w[0] + be[1]*w[1] + be[2]*w[2] + be[3]*w[3];
#pragma unroll
        for (int off = 32; off >= 1; off >>= 1) {
            a += __shfl_xor(a, off); b += __shfl_xor(b, off);
        }
        if (tid == 0) { sg[0] = a; sg[1] = b + bl[0]; }
    }

    // ---- A preload: 2112 chunks of 16B bf16 (h1pad rows t0 .. t0+65) ----
    const __bf16* hb = h1pad + ((size_t)bb * (T_ + 2) + t0) * D_;
#pragma unroll
    for (int i = 0; i < 5; ++i) {
        int c = tid + 512 * i;
        if (c < 2112) {
            int u = c >> 5, off = c & 31;
            bf16x8 v = *(const bf16x8*)(hb + (size_t)u * D_ + off * 8);
            *(bf16x8*)(&Axs[u * APITCH + off * 8]) = v;
        }
    }
    BSTAGE(0, 0); BSTAGE(1, 1);
    __syncthreads();

    f32x4 acc[4][2];
#pragma unroll
    for (int mf = 0; mf < 4; ++mf)
#pragma unroll
        for (int nf = 0; nf < 2; ++nf)
            acc[mf][nf] = (f32x4){0.f, 0.f, 0.f, 0.f};

    auto COMPUTE = [&](int kstep) {
        const int tap = kstep >> 3;
        const int co = (kstep & 7) * 64;
        const unsigned char* Ab = (const unsigned char*)Axs;
        unsigned char* Bb = Bring + (kstep % 3) * BBUF;
        const int swz = (q ^ (p & 3)) * 16;
        bf16x8 a[4], bv[2];
#pragma unroll
        for (int mf = 0; mf < 4; ++mf)
            a[mf] = *(const bf16x8*)(Ab + (mf * 16 + p + tap) * (APITCH * 2)
                                     + co + q * 16);
#pragma unroll
        for (int nf = 0; nf < 2; ++nf)
            bv[nf] = *(const bf16x8*)(Bb + (wid * 32 + nf * 16 + p) * 64 + swz);
#pragma unroll
        for (int mf = 0; mf < 4; ++mf)
#pragma unroll
            for (int nf = 0; nf < 2; ++nf)
                acc[mf][nf] = __builtin_amdgcn_mfma_f32_16x16x32_bf16(
                    a[mf], bv[nf], acc[mf][nf], 0, 0, 0);
    };

    RUN_PIPE(COMPUTE)

    float bcol[2], gwcol[2];
#pragma unroll
    for (int nf = 0; nf < 2; ++nf) {
        int c = wid * 32 + nf * 16 + p;
        bcol[nf]  = bias[c];
        gwcol[nf] = gamma[c] * wl[c];
    }
#pragma unroll
    for (int mf = 0; mf < 4; ++mf)
#pragma unroll
        for (int r = 0; r < 4; ++r) {
            float s = 0.f, s2 = 0.f, s3 = 0.f;
#pragma unroll
            for (int nf = 0; nf < 2; ++nf) {
                float y = fmaxf(acc[mf][nf][r] + bcol[nf], 0.f);
                s += y; s2 += y * y; s3 += y * gwcol[nf];
            }
#pragma unroll
            for (int off = 8; off >= 1; off >>= 1) {
                s  += __shfl_xor(s, off);
                s2 += __shfl_xor(s2, off);
                s3 += __shfl_xor(s3, off);
            }
            if (p == 0) {
                int row = mf * 16 + q * 4 + r;
                part[(row * 8 + wid) * 4]     = s;
                part[(row * 8 + wid) * 4 + 1] = s2;
                part[(row * 8 + wid) * 4 + 2] = s3;
            }
        }
    __syncthreads();
    if (tid < 64) {
        float s = 0.f, s2 = 0.f, s3 = 0.f;
#pragma unroll
        for (int w = 0; w < 8; ++w) {
            s  += part[(tid * 8 + w) * 4];
            s2 += part[(tid * 8 + w) * 4 + 1];
            s3 += part[(tid * 8 + w) * 4 + 2];
        }
        float m  = s * (1.f / 256.f);
        float v  = s2 * (1.f / 256.f) - m * m;
        float rs = rsqrtf(v + 1e-5f);
        pred[bb * T_ + t0 + tid] = rs * (s3 - m * sg[0]) + sg[1];
    }

    // ---- gather phase: grid-strided, 8 waves x 4 rows per iteration ----
    if (!doGather) return;
    const int NR = B_ * maxLen;
    for (int base = blockIdx.x * 32; base < NR; base += 256 * 32) {
        int rowBase = base + wid * 4;
        const float* src[4];
        int ok[4];
#pragma unroll
        for (int j = 0; j < 4; ++j) {
            int idx = rowBase + j;
            int b = idx / maxLen, m = idx - b * maxLen;
            ok[j] = (b < B_);
            src[j] = nullptr;
            if (ok[j]) {
                const int* e = ends + b * T_;
                if (m < e[T_ - 1]) {
                    int lo = 0, hi = T_ - 1;
                    while (lo < hi) {
                        int mid = (lo + hi) >> 1;
                        if (e[mid] > m) hi = mid; else lo = mid + 1;
                    }
                    src[j] = x + ((size_t)b * T_ + lo) * D_ + 4 * lane;
                }
            }
        }
        float4 v[4];
#pragma unroll
        for (int j = 0; j < 4; ++j)
            v[j] = src[j] ? *(const float4*)src[j]
                          : make_float4(0.f, 0.f, 0.f, 0.f);
#pragma unroll
        for (int j = 0; j < 4; ++j)
            if (ok[j])
                *(float4*)(out + (size_t)(rowBase + j) * D_ + 4 * lane) = v[j];
    }
}

// prep: scan (blocks 0..31) + weight transpose + h1pad halo rows.
__global__ __launch_bounds__(512) void prep_kernel(
    const int* __restrict__ td, const float* __restrict__ w1,
    const float* __restrict__ w2,
    int* __restrict__ ends,
    __bf16* __restrict__ bm1, __bf16* __restrict__ bm2,
    __bf16* __restrict__ h1pad)
{
    if (blockIdx.x < 32) {   // inclusive cumsum per batch
        __shared__ int s[T_];
        int b = blockIdx.x, t = threadIdx.x;
        s[t] = td[b * T_ + t];
        __syncthreads();
        for (int off = 1; off < T_; off <<= 1) {
            int add = (t >= off) ? s[t - off] : 0;
            __syncthreads();
            s[t] += add;
            __syncthreads();
        }
        ends[b * T_ + t] = s[t];
        return;
    }
    const int NW8 = D_ * KTOT / 8;       // 24,576 per conv
    const int NZ8 = B_ * 2 * D_ / 8;     // 2,048
    int idx = (blockIdx.x - 32) * 512 + threadIdx.x;
    if (idx < 2 * NW8) {
        int j = idx * 8;
        const float* ws = w1;
        __bf16* bm = bm1;
        if (j >= D_ * KTOT) { j -= D_ * KTOT; ws = w2; bm = bm2; }
        int n = j / KTOT;
        int kap = j - n * KTOT;
        int k = kap >> 8, i = kap & 255;
        bf16x8 o;
#pragma unroll
        for (int u = 0; u < 8; ++u)
            o[u] = (__bf16)ws[(n * D_ + i + u) * 3 + k];
        *(bf16x8*)(bm + n * KTOT + kap) = o;
    } else if (idx < 2 * NW8 + NZ8) {
        int j = (idx - 2 * NW8) * 8;
        int b = j >> 9, qq = (j >> 8) & 1, d = j & 255;
        bf16x8 o;
#pragma unroll
        for (int u = 0; u < 8; ++u) o[u] = (__bf16)0.f;
        *(bf16x8*)(h1pad + ((size_t)b * (T_ + 2) + (qq ? T_ + 1 : 0)) * D_ + d) = o;
    }
}

// Standalone gather (fallback when scratch is parked in d_out).
__global__ __launch_bounds__(256) void gather_kernel(
    const float* __restrict__ x, const int* __restrict__ ends,
    float* __restrict__ out, int maxLen)
{
    int tid = threadIdx.x, wd = tid >> 6, lane = tid & 63;
    int idx = blockIdx.x * 4 + wd;
    int b = idx / maxLen, m = idx % maxLen;
    if (b >= B_) return;
    const int* e = &ends[b * T_];
    float4 r = make_float4(0.f, 0.f, 0.f, 0.f);
    if (m < e[T_ - 1]) {
        int lo = 0, hi = T_ - 1;
        while (lo < hi) {
            int mid = (lo + hi) >> 1;
            if (e[mid] > m) hi = mid; else lo = mid + 1;
        }
        r = *(const float4*)(&x[((size_t)b * T_ + lo) * D_ + 4 * lane]);
    }
    *(float4*)(&out[((size_t)b * maxLen + m) * D_ + 4 * lane]) = r;
}

extern "C" void kernel_launch(void* const* d_in, const int* in_sizes, int n_in,
                              void* d_out, int out_size, void* d_ws, size_t ws_size,
                              hipStream_t stream) {
    const float* x   = (const float*)d_in[0];
    const int*   td  = (const int*)d_in[1];
    const float* w1  = (const float*)d_in[2];
    const float* b1  = (const float*)d_in[3];
    const float* g1  = (const float*)d_in[4];
    const float* be1 = (const float*)d_in[5];
    const float* w2  = (const float*)d_in[6];
    const float* b2  = (const float*)d_in[7];
    const float* g2  = (const float*)d_in[8];
    const float* be2 = (const float*)d_in[9];
    const float* wl  = (const float*)d_in[10];
    const float* bl  = (const float*)d_in[11];
    float* outp = (float*)d_out;

    const int BT = B_ * T_;
    const int maxLen = (out_size - BT) / (B_ * D_);
    float* predp = outp + (size_t)B_ * maxLen * D_;

    const size_t SZ_ENDS = 65536;
    const size_t SZ_H1   = (size_t)B_ * (T_ + 2) * D_ * 2;  // 8,421,376
    const size_t SZ_BM   = (size_t)D_ * KTOT * 2;           // 393,216
    const size_t need = SZ_ENDS + SZ_H1 + 2 * SZ_BM;

    int* endsp = (int*)d_ws;
    char* base;
    const bool inWs = (ws_size >= need);
    if (inWs) base = (char*)d_ws + SZ_ENDS;
    else      base = (char*)d_out;   // consumed before standalone gather overwrites

    __bf16* h1padp = (__bf16*)(base);
    __bf16* bm1p   = (__bf16*)(base + SZ_H1);
    __bf16* bm2p   = (__bf16*)(base + SZ_H1 + SZ_BM);

    const int NW8 = D_ * KTOT / 8, NZ8 = B_ * 2 * D_ / 8;
    const int prepBlocks = 32 + (2 * NW8 + NZ8 + 511) / 512;

    prep_kernel<<<prepBlocks, 512, 0, stream>>>(td, w1, w2, endsp, bm1p, bm2p, h1padp);
    gemm1_ln_kernel<<<BT / TILE_M, 512, 0, stream>>>(x, bm1p, b1, g1, be1, h1padp);
    gemm2_pred_gather_kernel<<<BT / TILE_M, 512, 0, stream>>>(
        h1padp, bm2p, b2, g2, be2, wl, bl, predp, x, endsp, outp, maxLen,
        inWs ? 1 : 0);
    if (!inWs)
        gather_kernel<<<(B_ * maxLen + 3) / 4, 256, 0, stream>>>(x, endsp, outp, maxLen);
}

// Round 12
// 54.943 us; speedup vs baseline: 1.7501x; 1.7501x over previous
//
#include <hip/hip_runtime.h>
#include <math.h>

#define B_ 32
#define T_ 512
#define D_ 256
#define KTOT 768             // 3 taps x 256 channels
#define NS2 12               // K-steps of 64
#define TILE_M 64
#define APITCH 264           // bf16 elems per A-LDS row (528B)
#define BBUF 32768           // one B stage: 256 rows x 64 bf16 (128B rows)

typedef __bf16 bf16x8 __attribute__((ext_vector_type(8)));
typedef __bf16 bf16x4 __attribute__((ext_vector_type(4)));
typedef float  f32x4  __attribute__((ext_vector_type(4)));

__device__ __forceinline__ void gload16(const void* g, void* l) {
    __builtin_amdgcn_global_load_lds(
        (const __attribute__((address_space(1))) unsigned int*)g,
        (__attribute__((address_space(3))) unsigned int*)l, 16, 0, 0);
}

// B stage (64 cols): 2048 chunks of 16B; 512 threads -> 4 loads/thread.
// Row = 128B; slot XOR (c&7)^(n&7) on the SOURCE; read undoes it.
#define BSTAGE(s, buf)                                                  \
    do {                                                                \
        _Pragma("unroll")                                               \
        for (int pp = 0; pp < 4; ++pp) {                                \
            int c = pp * 512 + tid;                                     \
            int n = c >> 3, scb = (c & 7) ^ (n & 7);                    \
            gload16(bmat + (size_t)n * KTOT + (s) * 64 + scb * 8,       \
                    Bring + (buf) * BBUF + c * 16);                     \
        }                                                               \
    } while (0)

// 12 iterations; 2 K=32 sub-steps per staged buffer; depth-2 prefetch.
#define RUN_PIPE(COMPUTE)                                               \
    BSTAGE(0, 0); BSTAGE(1, 1);                                         \
    __syncthreads();                                                    \
    _Pragma("unroll")                                                   \
    for (int s = 0; s < NS2; ++s) {                                     \
        if (s) {                                                        \
            if (s < NS2 - 1) asm volatile("s_waitcnt vmcnt(4)" ::: "memory"); \
            else             asm volatile("s_waitcnt vmcnt(0)" ::: "memory"); \
            __builtin_amdgcn_s_barrier();                               \
        }                                                               \
        if (s + 2 < NS2) BSTAGE(s + 2, (s + 2) % 3);                    \
        COMPUTE(2 * s); COMPUTE(2 * s + 1);                             \
    }

// ---------------------------------------------------------------------------
// conv1: A = 66 fp32 x-rows preloaded once -> bf16 LDS [66][264]; B ring-3
// staged 64 cols at a time.  512 thr / 8 waves; wave = 64 rows x 32 cols.
// Epilogue: bias/ReLU/LayerNorm -> bf16 h1pad rows 1..512.
// ---------------------------------------------------------------------------
__global__ __launch_bounds__(512) void gemm1_ln_kernel(
    const float* __restrict__ x,       // (B,512,256) fp32
    const __bf16* __restrict__ bmat,   // (256,768)
    const float* __restrict__ bias,
    const float* __restrict__ gamma,
    const float* __restrict__ beta,
    __bf16* __restrict__ dst)          // h1pad (B,514,256)
{
    __shared__ __align__(16) __bf16 Axs[66 * APITCH];
    __shared__ __align__(16) unsigned char Bring[3 * BBUF];
    __shared__ float part[64 * 8 * 2];
    __shared__ float tot[64 * 2];
    const int tid = threadIdx.x, lane = tid & 63, wid = tid >> 6;
    const int p = lane & 15, q = lane >> 4;
    const int m0 = blockIdx.x * TILE_M;
    const int bb = m0 >> 9, t0 = m0 & 511;
    const float* xb = x + (size_t)bb * T_ * D_;

    // ---- A preload: 4224 chunks of 4 f32 -> cvt -> 8B LDS write ----
#pragma unroll
    for (int i = 0; i < 9; ++i) {
        int c = tid + 512 * i;
        if (c < 4224) {
            int u = c >> 6, cf = c & 63;
            int t = t0 - 1 + u;
            bool v = ((unsigned)t < (unsigned)T_);
            f32x4 xv = *(const f32x4*)(xb + (size_t)(v ? t : 0) * D_ + cf * 4);
            bf16x4 o;
#pragma unroll
            for (int e = 0; e < 4; ++e) o[e] = (__bf16)(v ? xv[e] : 0.f);
            *(bf16x4*)(&Axs[u * APITCH + cf * 4]) = o;
        }
    }

    f32x4 acc[4][2];
#pragma unroll
    for (int mf = 0; mf < 4; ++mf)
#pragma unroll
        for (int nf = 0; nf < 2; ++nf)
            acc[mf][nf] = (f32x4){0.f, 0.f, 0.f, 0.f};

    auto COMPUTE = [&](int kstep) {
        const int tap = kstep >> 3;
        const int co = (kstep & 7) * 64;   // byte col offset within A row
        unsigned char* Bb = Bring + ((kstep >> 1) % 3) * BBUF;
        bf16x8 a[4], bv[2];
#pragma unroll
        for (int mf = 0; mf < 4; ++mf)
            a[mf] = *(const bf16x8*)((const unsigned char*)Axs
                     + (mf * 16 + p + tap) * (APITCH * 2) + co + q * 16);
#pragma unroll
        for (int nf = 0; nf < 2; ++nf) {
            int row = wid * 32 + nf * 16 + p;
            int phys = (((kstep & 1) << 2) + q) ^ (p & 7);
            bv[nf] = *(const bf16x8*)(Bb + row * 128 + phys * 16);
        }
#pragma unroll
        for (int mf = 0; mf < 4; ++mf)
#pragma unroll
            for (int nf = 0; nf < 2; ++nf)
                acc[mf][nf] = __builtin_amdgcn_mfma_f32_16x16x32_bf16(
                    a[mf], bv[nf], acc[mf][nf], 0, 0, 0);
    };

    RUN_PIPE(COMPUTE)

    // ---- epilogue: bias+ReLU -> cross-wave LN -> bf16 h1pad ----
    float bcol[2], gcol[2], becol[2];
#pragma unroll
    for (int nf = 0; nf < 2; ++nf) {
        int c = wid * 32 + nf * 16 + p;
        bcol[nf] = bias[c]; gcol[nf] = gamma[c]; becol[nf] = beta[c];
    }
#pragma unroll
    for (int mf = 0; mf < 4; ++mf)
#pragma unroll
        for (int r = 0; r < 4; ++r) {
            float s = 0.f, s2 = 0.f;
#pragma unroll
            for (int nf = 0; nf < 2; ++nf) {
                float y = fmaxf(acc[mf][nf][r] + bcol[nf], 0.f);
                s += y; s2 += y * y;
            }
#pragma unroll
            for (int off = 8; off >= 1; off >>= 1) {
                s += __shfl_xor(s, off); s2 += __shfl_xor(s2, off);
            }
            if (p == 0) {
                int row = mf * 16 + q * 4 + r;
                part[(row * 8 + wid) * 2]     = s;
                part[(row * 8 + wid) * 2 + 1] = s2;
            }
        }
    __syncthreads();
    if (tid < 64) {
        float s = 0.f, s2 = 0.f;
#pragma unroll
        for (int w = 0; w < 8; ++w) {
            s  += part[(tid * 8 + w) * 2];
            s2 += part[(tid * 8 + w) * 2 + 1];
        }
        float m = s * (1.f / 256.f);
        float v = s2 * (1.f / 256.f) - m * m;
        tot[tid * 2]     = m;
        tot[tid * 2 + 1] = rsqrtf(v + 1e-5f);
    }
    __syncthreads();
#pragma unroll
    for (int mf = 0; mf < 4; ++mf)
#pragma unroll
        for (int r = 0; r < 4; ++r) {
            int row = mf * 16 + q * 4 + r;
            float m  = tot[row * 2];
            float rs = tot[row * 2 + 1];
            size_t gb = ((size_t)bb * (T_ + 2) + 1 + t0 + row) * D_;
#pragma unroll
            for (int nf = 0; nf < 2; ++nf) {
                int c = wid * 32 + nf * 16 + p;
                float y = fmaxf(acc[mf][nf][r] + bcol[nf], 0.f);
                dst[gb + c] = (__bf16)((y - m) * rs * gcol[nf] + becol[nf]);
            }
        }
}

// ---------------------------------------------------------------------------
// conv2: A = 66 bf16 h1pad rows preloaded once; B ring-staged (64-col).
// Epilogue folds LN + (h@wl+bl): pred = rstd*(S3 - mean*Sgw) + Sbw.
// ---------------------------------------------------------------------------
__global__ __launch_bounds__(512) void gemm2_pred_kernel(
    const __bf16* __restrict__ h1pad,  // (B, 514, 256)
    const __bf16* __restrict__ bmat,
    const float* __restrict__ bias,
    const float* __restrict__ gamma,
    const float* __restrict__ beta,
    const float* __restrict__ wl,
    const float* __restrict__ bl,
    float* __restrict__ pred)          // (B, T)
{
    __shared__ __align__(16) __bf16 Axs[66 * APITCH];
    __shared__ __align__(16) unsigned char Bring[3 * BBUF];
    __shared__ float part[64 * 8 * 4];
    __shared__ float sg[2];
    const int tid = threadIdx.x, lane = tid & 63, wid = tid >> 6;
    const int p = lane & 15, q = lane >> 4;
    const int m0 = blockIdx.x * TILE_M;
    const int bb = m0 >> 9, t0 = m0 & 511;

    if (tid < 64) {   // Sgw = sum g*wl, Sbw = sum be*wl + bl
        f32x4 g  = *(const f32x4*)(gamma + 4 * tid);
        f32x4 be = *(const f32x4*)(beta  + 4 * tid);
        f32x4 w  = *(const f32x4*)(wl    + 4 * tid);
        float a = g[0]*w[0] + g[1]*w[1] + g[2]*w[2] + g[3]*w[3];
        float b = be[0]*w[0] + be[1]*w[1] + be[2]*w[2] + be[3]*w[3];
#pragma unroll
        for (int off = 32; off >= 1; off >>= 1) {
            a += __shfl_xor(a, off); b += __shfl_xor(b, off);
        }
        if (tid == 0) { sg[0] = a; sg[1] = b + bl[0]; }
    }

    // ---- A preload: 2112 chunks of 16B bf16 (h1pad rows t0 .. t0+65) ----
    const __bf16* hb = h1pad + ((size_t)bb * (T_ + 2) + t0) * D_;
#pragma unroll
    for (int i = 0; i < 5; ++i) {
        int c = tid + 512 * i;
        if (c < 2112) {
            int u = c >> 5, off = c & 31;
            bf16x8 v = *(const bf16x8*)(hb + (size_t)u * D_ + off * 8);
            *(bf16x8*)(&Axs[u * APITCH + off * 8]) = v;
        }
    }

    f32x4 acc[4][2];
#pragma unroll
    for (int mf = 0; mf < 4; ++mf)
#pragma unroll
        for (int nf = 0; nf < 2; ++nf)
            acc[mf][nf] = (f32x4){0.f, 0.f, 0.f, 0.f};

    auto COMPUTE = [&](int kstep) {
        const int tap = kstep >> 3;
        const int co = (kstep & 7) * 64;
        unsigned char* Bb = Bring + ((kstep >> 1) % 3) * BBUF;
        bf16x8 a[4], bv[2];
#pragma unroll
        for (int mf = 0; mf < 4; ++mf)
            a[mf] = *(const bf16x8*)((const unsigned char*)Axs
                     + (mf * 16 + p + tap) * (APITCH * 2) + co + q * 16);
#pragma unroll
        for (int nf = 0; nf < 2; ++nf) {
            int row = wid * 32 + nf * 16 + p;
            int phys = (((kstep & 1) << 2) + q) ^ (p & 7);
            bv[nf] = *(const bf16x8*)(Bb + row * 128 + phys * 16);
        }
#pragma unroll
        for (int mf = 0; mf < 4; ++mf)
#pragma unroll
            for (int nf = 0; nf < 2; ++nf)
                acc[mf][nf] = __builtin_amdgcn_mfma_f32_16x16x32_bf16(
                    a[mf], bv[nf], acc[mf][nf], 0, 0, 0);
    };

    RUN_PIPE(COMPUTE)

    float bcol[2], gwcol[2];
#pragma unroll
    for (int nf = 0; nf < 2; ++nf) {
        int c = wid * 32 + nf * 16 + p;
        bcol[nf]  = bias[c];
        gwcol[nf] = gamma[c] * wl[c];
    }
#pragma unroll
    for (int mf = 0; mf < 4; ++mf)
#pragma unroll
        for (int r = 0; r < 4; ++r) {
            float s = 0.f, s2 = 0.f, s3 = 0.f;
#pragma unroll
            for (int nf = 0; nf < 2; ++nf) {
                float y = fmaxf(acc[mf][nf][r] + bcol[nf], 0.f);
                s += y; s2 += y * y; s3 += y * gwcol[nf];
            }
#pragma unroll
            for (int off = 8; off >= 1; off >>= 1) {
                s  += __shfl_xor(s, off);
                s2 += __shfl_xor(s2, off);
                s3 += __shfl_xor(s3, off);
            }
            if (p == 0) {
                int row = mf * 16 + q * 4 + r;
                part[(row * 8 + wid) * 4]     = s;
                part[(row * 8 + wid) * 4 + 1] = s2;
                part[(row * 8 + wid) * 4 + 2] = s3;
            }
        }
    __syncthreads();
    if (tid < 64) {
        float s = 0.f, s2 = 0.f, s3 = 0.f;
#pragma unroll
        for (int w = 0; w < 8; ++w) {
            s  += part[(tid * 8 + w) * 4];
            s2 += part[(tid * 8 + w) * 4 + 1];
            s3 += part[(tid * 8 + w) * 4 + 2];
        }
        float m  = s * (1.f / 256.f);
        float v  = s2 * (1.f / 256.f) - m * m;
        float rs = rsqrtf(v + 1e-5f);
        pred[bb * T_ + t0 + tid] = rs * (s3 - m * sg[0]) + sg[1];
    }
}

// prep: scan+map (blocks 0..31) + weight transpose + h1pad halo rows.
// map[b*maxLen+m] = absolute x-row (b*T+t) or -1 (expansion scatter).
__global__ __launch_bounds__(512) void prep_kernel(
    const int* __restrict__ td, const float* __restrict__ w1,
    const float* __restrict__ w2,
    int* __restrict__ ends, int* __restrict__ map,
    __bf16* __restrict__ bm1, __bf16* __restrict__ bm2,
    __bf16* __restrict__ h1pad, int maxLen)
{
    if (blockIdx.x < 32) {   // inclusive cumsum per batch + map scatter
        __shared__ int s[T_];
        int b = blockIdx.x, t = threadIdx.x;
        int d0 = td[b * T_ + t];
        s[t] = d0;
        __syncthreads();
        for (int off = 1; off < T_; off <<= 1) {
            int add = (t >= off) ? s[t - off] : 0;
            __syncthreads();
            s[t] += add;
            __syncthreads();
        }
        int e = s[t];
        ends[b * T_ + t] = e;
        if (map) {
            int* mp = map + b * maxLen;
            int src = b * T_ + t;
            for (int j = e - d0; j < e; ++j) mp[j] = src;
            int lens = s[T_ - 1];
            for (int m = lens + t; m < maxLen; m += T_) mp[m] = -1;
        }
        return;
    }
    const int NW8 = D_ * KTOT / 8;       // 24,576 per conv
    const int NZ8 = B_ * 2 * D_ / 8;     // 2,048
    int idx = (blockIdx.x - 32) * 512 + threadIdx.x;
    if (idx < 2 * NW8) {
        int j = idx * 8;
        const float* ws = w1;
        __bf16* bm = bm1;
        if (j >= D_ * KTOT) { j -= D_ * KTOT; ws = w2; bm = bm2; }
        int n = j / KTOT;
        int kap = j - n * KTOT;
        int k = kap >> 8, i = kap & 255;
        bf16x8 o;
#pragma unroll
        for (int u = 0; u < 8; ++u)
            o[u] = (__bf16)ws[(n * D_ + i + u) * 3 + k];
        *(bf16x8*)(bm + n * KTOT + kap) = o;
    } else if (idx < 2 * NW8 + NZ8) {
        int j = (idx - 2 * NW8) * 8;
        int b = j >> 9, qq = (j >> 8) & 1, d = j & 255;
        bf16x8 o;
#pragma unroll
        for (int u = 0; u < 8; ++u) o[u] = (__bf16)0.f;
        *(bf16x8*)(h1pad + ((size_t)b * (T_ + 2) + (qq ? T_ + 1 : 0)) * D_ + d) = o;
    }
}

// Map-based gather: one dependent L2 load, then a pure row copy.
__global__ __launch_bounds__(256) void gather_map_kernel(
    const float* __restrict__ x, const int* __restrict__ map,
    float* __restrict__ out, int maxLen)
{
    int tid = threadIdx.x, wd = tid >> 6, lane = tid & 63;
    int idx = blockIdx.x * 4 + wd;
    if (idx >= B_ * maxLen) return;
    int src = map[idx];
    float4 r = make_float4(0.f, 0.f, 0.f, 0.f);
    if (src >= 0)
        r = *(const float4*)(x + (size_t)src * D_ + 4 * lane);
    *(float4*)(out + (size_t)idx * D_ + 4 * lane) = r;
}

// Fallback binary-search gather (if ws can't hold the map).
__global__ __launch_bounds__(256) void gather_kernel(
    const float* __restrict__ x, const int* __restrict__ ends,
    float* __restrict__ out, int maxLen)
{
    int tid = threadIdx.x, wd = tid >> 6, lane = tid & 63;
    int idx = blockIdx.x * 4 + wd;
    int b = idx / maxLen, m = idx % maxLen;
    if (b >= B_) return;
    const int* e = &ends[b * T_];
    float4 r = make_float4(0.f, 0.f, 0.f, 0.f);
    if (m < e[T_ - 1]) {
        int lo = 0, hi = T_ - 1;
        while (lo < hi) {
            int mid = (lo + hi) >> 1;
            if (e[mid] > m) hi = mid; else lo = mid + 1;
        }
        r = *(const float4*)(&x[((size_t)b * T_ + lo) * D_ + 4 * lane]);
    }
    *(float4*)(&out[((size_t)b * maxLen + m) * D_ + 4 * lane]) = r;
}

extern "C" void kernel_launch(void* const* d_in, const int* in_sizes, int n_in,
                              void* d_out, int out_size, void* d_ws, size_t ws_size,
                              hipStream_t stream) {
    const float* x   = (const float*)d_in[0];
    const int*   td  = (const int*)d_in[1];
    const float* w1  = (const float*)d_in[2];
    const float* b1  = (const float*)d_in[3];
    const float* g1  = (const float*)d_in[4];
    const float* be1 = (const float*)d_in[5];
    const float* w2  = (const float*)d_in[6];
    const float* b2  = (const float*)d_in[7];
    const float* g2  = (const float*)d_in[8];
    const float* be2 = (const float*)d_in[9];
    const float* wl  = (const float*)d_in[10];
    const float* bl  = (const float*)d_in[11];
    float* outp = (float*)d_out;

    const int BT = B_ * T_;
    const int maxLen = (out_size - BT) / (B_ * D_);
    float* predp = outp + (size_t)B_ * maxLen * D_;

    const size_t SZ_ENDS = 65536;
    const size_t SZ_MAP  = (((size_t)B_ * maxLen * 4) + 1023) & ~(size_t)1023;
    const size_t SZ_H1   = (size_t)B_ * (T_ + 2) * D_ * 2;  // 8,421,376
    const size_t SZ_BM   = (size_t)D_ * KTOT * 2;           // 393,216
    const size_t need = SZ_ENDS + SZ_MAP + SZ_H1 + 2 * SZ_BM;

    int* endsp = (int*)d_ws;
    const bool haveMap = (ws_size >= SZ_ENDS + SZ_MAP);
    int* mapp = haveMap ? (int*)((char*)d_ws + SZ_ENDS) : nullptr;
    char* base;
    if (ws_size >= need) base = (char*)d_ws + SZ_ENDS + SZ_MAP;
    else                 base = (char*)d_out;  // consumed before gather overwrites

    __bf16* h1padp = (__bf16*)(base);
    __bf16* bm1p   = (__bf16*)(base + SZ_H1);
    __bf16* bm2p   = (__bf16*)(base + SZ_H1 + SZ_BM);

    const int NW8 = D_ * KTOT / 8, NZ8 = B_ * 2 * D_ / 8;
    const int prepBlocks = 32 + (2 * NW8 + NZ8 + 511) / 512;

    prep_kernel<<<prepBlocks, 512, 0, stream>>>(td, w1, w2, endsp, mapp,
                                                bm1p, bm2p, h1padp, maxLen);
    gemm1_ln_kernel<<<BT / TILE_M, 512, 0, stream>>>(x, bm1p, b1, g1, be1, h1padp);
    gemm2_pred_kernel<<<BT / TILE_M, 512, 0, stream>>>(h1padp, bm2p, b2, g2, be2,
                                                       wl, bl, predp);
    const int gBlocks = (B_ * maxLen + 3) / 4;
    if (haveMap)
        gather_map_kernel<<<gBlocks, 256, 0, stream>>>(x, mapp, outp, maxLen);
    else
        gather_kernel<<<gBlocks, 256, 0, stream>>>(x, endsp, outp, maxLen);
}